// Round 2
// baseline (8812.310 us; speedup 1.0000x reference)
//
#include <hip/hip_runtime.h>
#include <hip/hip_bf16.h>
#include <cstdint>
#include <cstddef>

typedef __attribute__((ext_vector_type(8))) short bf16x8;
typedef __attribute__((ext_vector_type(4))) short bf16x4;
typedef __attribute__((ext_vector_type(4))) float f32x4;

#define LOG2E 1.442695041f

__device__ __forceinline__ float bf2f(short s){
  unsigned int u = ((unsigned int)(unsigned short)s) << 16;
  return __builtin_bit_cast(float, u);
}
__device__ __forceinline__ short f2bf(float f){
  unsigned int u = __builtin_bit_cast(unsigned int, f);
  unsigned int r = (u + 0x7fff + ((u >> 16) & 1)) >> 16;
  return (short)r;
}
__device__ __forceinline__ float sigm(float x){
  return __builtin_amdgcn_rcpf(1.f + __builtin_amdgcn_exp2f(-LOG2E * x));
}
__device__ __forceinline__ float tanh_(float x){
  return 1.f - 2.f * __builtin_amdgcn_rcpf(1.f + __builtin_amdgcn_exp2f(2.f * LOG2E * x));
}
// permuted column np -> original gate column. np = w*256 + gate*64 + ul, orig = gate*256 + w*64 + ul
__device__ __forceinline__ int orig_col(int np){
  int w = np >> 8, rem = np & 255, gate = rem >> 6, ul = rem & 63;
  return gate * 256 + w * 64 + ul;
}

// ---------------- prep kernels ----------------
__global__ void k_prep_wipT(const float* __restrict__ Wi, short* __restrict__ outT, int K){
  int idx = blockIdx.x * 256 + threadIdx.x;      // over 1024*K/8
  int kv = K >> 3;
  int np = idx / kv, k0 = (idx % kv) * 8;
  int oc = orig_col(np);
  bf16x8 v;
  #pragma unroll
  for (int j = 0; j < 8; ++j) v[j] = f2bf(Wi[(size_t)(k0 + j) * 1024 + oc]);
  *(bf16x8*)(outT + (size_t)np * K + k0) = v;
}

__global__ void k_prep_bias(const float* __restrict__ b, float* __restrict__ bp){
  int np = blockIdx.x * 256 + threadIdx.x;
  bp[np] = b[orig_col(np)];
}

// Wh [256,1024] f32 -> frag-tiled bf16
__global__ void k_prep_wht(const float* __restrict__ Wh, short* __restrict__ wht){
  int idx = blockIdx.x * 256 + threadIdx.x;      // 32768 threads
  int l = idx & 63, fk = idx >> 6, kk = fk & 7, ng = fk >> 3;
  int oc = orig_col(ng * 16 + (l & 15));
  int kbase = kk * 32 + ((l >> 4) << 3);
  bf16x8 v;
  #pragma unroll
  for (int j = 0; j < 8; ++j) v[j] = f2bf(Wh[(size_t)(kbase + j) * 1024 + oc]);
  *(bf16x8*)(wht + (size_t)idx * 8) = v;
}

// embedding gather: x1t[(t*64+b)][k] = bf16(embed[tokens[b][t]][k])
__global__ void k_gather(const int* __restrict__ tokens, const float* __restrict__ embed,
                         short* __restrict__ x1t){
  int v = blockIdx.x * 256 + threadIdx.x;
  const int total = 64 * 1024 * 256 / 4;
  for (; v < total; v += gridDim.x * 256){
    int e = v * 4;
    int row = e >> 8, k = e & 255;
    int t = row >> 6, b = row & 63;
    int tok = tokens[b * 1024 + t];
    f32x4 f = *(const f32x4*)(embed + (size_t)tok * 256 + k);
    bf16x4 o4;
    #pragma unroll
    for (int j = 0; j < 4; ++j) o4[j] = f2bf(f[j]);
    *(bf16x4*)(x1t + e) = o4;
  }
}

// ---------------- input-projection GEMM (chunk of timesteps) ----------------
// A [S*64, K] bf16 (rows lt*64+b), BT [1024][K] bf16 (permuted cols), bias f32[1024]
// out xw bf16 frag-tiled: ((lt*4+cb)*64 + ng)*256 + l*4 + r
template<int K>
__global__ __launch_bounds__(256)
void k_gemm(const short* __restrict__ A, const short* __restrict__ BT,
            const float* __restrict__ bias, short* __restrict__ xw){
  __shared__ short ldsA[128 * 72];
  __shared__ short ldsB[128 * 72];
  int tid = threadIdx.x;
  int l = tid & 63, wid = tid >> 6, wm = wid >> 1, wn = wid & 1;
  int M0 = blockIdx.x * 128, N0 = blockIdx.y * 128;
  f32x4 acc[4][4] = {};
  for (int kt = 0; kt < K / 64; ++kt){
    __syncthreads();
    for (int i = tid; i < 1024; i += 256){
      int row = i >> 3, seg = i & 7;
      *(bf16x8*)&ldsA[row * 72 + seg * 8] = *(const bf16x8*)&A[(size_t)(M0 + row) * K + kt * 64 + seg * 8];
      *(bf16x8*)&ldsB[row * 72 + seg * 8] = *(const bf16x8*)&BT[(size_t)(N0 + row) * K + kt * 64 + seg * 8];
    }
    __syncthreads();
    #pragma unroll
    for (int kk = 0; kk < 2; ++kk){
      int koff = kk * 32 + ((l >> 4) << 3);
      bf16x8 af[4], bfm[4];
      #pragma unroll
      for (int mt = 0; mt < 4; ++mt) af[mt] = *(const bf16x8*)&ldsA[(wm * 64 + mt * 16 + (l & 15)) * 72 + koff];
      #pragma unroll
      for (int nt = 0; nt < 4; ++nt) bfm[nt] = *(const bf16x8*)&ldsB[(wn * 64 + nt * 16 + (l & 15)) * 72 + koff];
      #pragma unroll
      for (int mt = 0; mt < 4; ++mt)
        #pragma unroll
        for (int nt = 0; nt < 4; ++nt)
          acc[mt][nt] = __builtin_amdgcn_mfma_f32_16x16x32_bf16(af[mt], bfm[nt], acc[mt][nt], 0, 0, 0);
    }
  }
  int t = blockIdx.x * 2 + wm;   // chunk-local t
  #pragma unroll
  for (int mt = 0; mt < 4; ++mt){
    #pragma unroll
    for (int nt = 0; nt < 4; ++nt){
      int ng = (N0 >> 4) + wn * 4 + nt;
      float bs = bias[ng * 16 + (l & 15)];
      bf16x4 ov;
      #pragma unroll
      for (int r = 0; r < 4; ++r) ov[r] = f2bf(acc[mt][nt][r] + bs);
      *(bf16x4*)&xw[((size_t)(t * 4 + mt) * 64 + ng) * 256 + l * 4] = ov;
    }
  }
}

// ---------------- recurrence (chunk of S steps) ----------------
// One WG per (dir, batch-chunk-16). 256 threads = 4 waves, 1 wave/SIMD.
// Wh resident: 91 frags/wave in VGPR/AGPR + 37 frags/wave in LDS (148KB). h in LDS (8KB swizzled).
template<int WRITE_SEQ>
__global__ __launch_bounds__(256, 1)
void k_recur(const short* __restrict__ xw_f, const short* __restrict__ xw_b,
             const short* __restrict__ wht_f, const short* __restrict__ wht_b,
             short* __restrict__ outp, float* __restrict__ cstate, short* __restrict__ hstate,
             int t0, int S, int two_dirs, int first)
{
  extern __shared__ char lds[];
  short* ldsB = (short*)lds;                 // 4 waves * 37 frags * 1024B = 151552
  char*  ldsH = lds + 151552;                // 16 x 512B = 8192
  int g = blockIdx.x;
  int d  = two_dirs ? (g >> 2) : 0;
  int cb = two_dirs ? (g & 3) : g;
  const short* xw  = d ? xw_b : xw_f;
  const short* wht = d ? wht_b : wht_f;
  int tid = threadIdx.x, w = tid >> 6, l = tid & 63;
  short* ldsBw = ldsB + (size_t)w * 37 * 64 * 8;

  // resident B fragments in regs: kk 0..4 all n (80) + kk==5 n<11 (11) = 91
  bf16x8 Breg[91];
  #pragma unroll
  for (int kk = 0; kk < 5; ++kk)
    #pragma unroll
    for (int n = 0; n < 16; ++n)
      Breg[kk * 16 + n] = *(const bf16x8*)&wht[(((size_t)(w * 16 + n) * 8 + kk) * 64 + l) * 8];
  #pragma unroll
  for (int n = 0; n < 11; ++n)
    Breg[80 + n] = *(const bf16x8*)&wht[(((size_t)(w * 16 + n) * 8 + 5) * 64 + l) * 8];

  // LDS B fragments: kk5 n11..15 -> slot 0..4 ; kk6 -> 5+n ; kk7 -> 21+n
  for (int s = 0; s < 37; ++s){
    int kk, n;
    if (s < 5)      { kk = 5; n = 11 + s; }
    else if (s < 21){ kk = 6; n = s - 5; }
    else            { kk = 7; n = s - 21; }
    *(bf16x8*)&ldsBw[(s * 64 + l) * 8] =
        *(const bf16x8*)&wht[(((size_t)(w * 16 + n) * 8 + kk) * 64 + l) * 8];
  }

  // h init (swizzled LDS) + c state
  f32x4 cst[4];
  if (first){
    for (int i = tid; i < 4096; i += 256) ((short*)ldsH)[i] = 0;
    #pragma unroll
    for (int q = 0; q < 4; ++q) cst[q] = f32x4{0.f,0.f,0.f,0.f};
  } else {
    #pragma unroll
    for (int it = 0; it < 2; ++it){
      int c = it * 256 + tid;
      int row = c >> 5, o16 = c & 31;
      bf16x8 hv = *(const bf16x8*)&hstate[((size_t)d * 64 + cb * 16 + row) * 256 + o16 * 8];
      *(bf16x8*)(ldsH + ((row * 512 + o16 * 16) ^ ((row & 7) << 4))) = hv;
    }
    #pragma unroll
    for (int q = 0; q < 4; ++q)
      #pragma unroll
      for (int r = 0; r < 4; ++r){
        int batch = ((l >> 4) << 2) + r, unit = w * 64 + q * 16 + (l & 15);
        cst[q][r] = cstate[((size_t)d * 64 + cb * 16 + batch) * 256 + unit];
      }
  }
  __syncthreads();

  // x prefetch for first step
  bf16x4 px[16];
  {
    int lt0 = d ? (S - 1) : 0;
    const short* xwn = xw + ((size_t)(lt0 * 4 + cb) * 64) * 256;
    #pragma unroll
    for (int n = 0; n < 16; ++n) px[n] = *(const bf16x4*)&xwn[((w * 16 + n) * 64 + l) * 4];
  }

  #pragma unroll 1
  for (int s = 0; s < S; ++s){
    // A fragments of h (current step) — must be read by ALL waves before any h overwrite
    bf16x8 af[8];
    #pragma unroll
    for (int kk = 0; kk < 8; ++kk)
      af[kk] = *(const bf16x8*)(ldsH + ((((l & 15) * 512) + kk * 64 + ((l >> 4) << 4)) ^ ((l & 7) << 4)));
    __syncthreads();   // barrier A: everyone read h

    int t = d ? (1023 - t0 - s) : (t0 + s);
    #pragma unroll
    for (int q = 0; q < 4; ++q){
      f32x4 acc[4];
      #pragma unroll
      for (int j = 0; j < 4; ++j){
        int n = 4 * j + q;
        #pragma unroll
        for (int r = 0; r < 4; ++r) acc[j][r] = bf2f(px[n][r]);
      }
      if (q == 3){ // prefetch x for next step (consumed next iteration)
        int sn = (s + 1 < S) ? s + 1 : s;
        int ltn = d ? (S - 1 - sn) : sn;
        const short* xwn = xw + ((size_t)(ltn * 4 + cb) * 64) * 256;
        #pragma unroll
        for (int n = 0; n < 16; ++n) px[n] = *(const bf16x4*)&xwn[((w * 16 + n) * 64 + l) * 4];
      }
      #pragma unroll
      for (int kk = 0; kk < 8; ++kk){
        #pragma unroll
        for (int j = 0; j < 4; ++j){
          int n = 4 * j + q;
          bf16x8 bfr;
          if (kk < 5)                  bfr = Breg[kk * 16 + n];
          else if (kk == 5 && n < 11)  bfr = Breg[80 + n];
          else {
            int slot = (kk == 5) ? (n - 11) : ((kk == 6) ? (5 + n) : (21 + n));
            bfr = *(const bf16x8*)&ldsBw[(slot * 64 + l) * 8];
          }
          acc[j] = __builtin_amdgcn_mfma_f32_16x16x32_bf16(af[kk], bfr, acc[j], 0, 0, 0);
        }
      }
      // gates: j = 0..3 -> i,f,g,o for unit w*64+q*16+(l&15)
      #pragma unroll
      for (int r = 0; r < 4; ++r){
        float ii = sigm(acc[0][r]), ff = sigm(acc[1][r]), gg = tanh_(acc[2][r]), oo = sigm(acc[3][r]);
        float cc = ff * cst[q][r] + ii * gg;
        cst[q][r] = cc;
        float hh = oo * tanh_(cc);
        short hb = f2bf(hh);
        int hrow = ((l >> 4) << 2) + r, hcol = w * 64 + q * 16 + (l & 15);
        *(short*)(ldsH + ((hrow * 512 + hcol * 2) ^ ((hrow & 7) << 4))) = hb;
        if (WRITE_SEQ)
          outp[((size_t)t * 64 + cb * 16 + hrow) * 512 + (size_t)d * 256 + hcol] = hb;
      }
    }
    __syncthreads();   // barrier B: h complete for next step
  }

  // save state for next chunk
  #pragma unroll
  for (int it = 0; it < 2; ++it){
    int c = it * 256 + tid;
    int row = c >> 5, o16 = c & 31;
    bf16x8 hv = *(const bf16x8*)(ldsH + ((row * 512 + o16 * 16) ^ ((row & 7) << 4)));
    *(bf16x8*)&hstate[((size_t)d * 64 + cb * 16 + row) * 256 + o16 * 8] = hv;
  }
  #pragma unroll
  for (int q = 0; q < 4; ++q)
    #pragma unroll
    for (int r = 0; r < 4; ++r){
      int batch = ((l >> 4) << 2) + r, unit = w * 64 + q * 16 + (l & 15);
      cstate[((size_t)d * 64 + cb * 16 + batch) * 256 + unit] = cst[q][r];
    }
}

// ---------------- layer-2 bwd single step ----------------
__global__ void k_h2b(const short* __restrict__ x2t, const float* __restrict__ Wi,
                      const float* __restrict__ bias, float* __restrict__ h2b){
  __shared__ float xr[512];
  int b = blockIdx.x, tid = threadIdx.x;
  for (int i = tid; i < 512; i += 256) xr[i] = bf2f(x2t[((size_t)1023 * 64 + b) * 512 + i]);
  __syncthreads();
  int u = tid;
  float s0 = bias[u], s1 = bias[256 + u], s2 = bias[512 + u], s3 = bias[768 + u];
  for (int k = 0; k < 512; ++k){
    float x = xr[k];
    const float* wr = Wi + (size_t)k * 1024;
    s0 += x * wr[u];       s1 += x * wr[256 + u];
    s2 += x * wr[512 + u]; s3 += x * wr[768 + u];
  }
  float cc = sigm(s0) * tanh_(s2);          // c0 = 0 -> f-term drops
  float hh = sigm(s3) * tanh_(cc);
  (void)s1;
  h2b[(size_t)b * 256 + u] = hh;
}

__global__ void k_logits(const short* __restrict__ h2f, const float* __restrict__ h2b,
                         const float* __restrict__ Wd, const float* __restrict__ bd,
                         float* __restrict__ out){
  int b = threadIdx.x;          // 64 threads
  float s = bd[0];
  for (int k = 0; k < 256; ++k) s += bf2f(h2f[b * 256 + k]) * Wd[k];
  for (int k = 0; k < 256; ++k) s += h2b[(size_t)b * 256 + k] * Wd[256 + k];
  out[b] = sigm(s);
}

// ---------------- host ----------------
extern "C" void kernel_launch(void* const* d_in, const int* in_sizes, int n_in,
                              void* d_out, int out_size, void* d_ws, size_t ws_size,
                              hipStream_t stream)
{
  (void)in_sizes; (void)n_in; (void)out_size;
  const int*   tokens = (const int*)d_in[0];
  const float* embed  = (const float*)d_in[1];
  const float* fw1_Wi = (const float*)d_in[2];
  const float* fw1_Wh = (const float*)d_in[3];
  const float* fw1_b  = (const float*)d_in[4];
  const float* bw1_Wi = (const float*)d_in[5];
  const float* bw1_Wh = (const float*)d_in[6];
  const float* bw1_b  = (const float*)d_in[7];
  const float* fw2_Wi = (const float*)d_in[8];
  const float* fw2_Wh = (const float*)d_in[9];
  const float* fw2_b  = (const float*)d_in[10];
  const float* bw2_Wi = (const float*)d_in[11];
  const float* bw2_Wh = (const float*)d_in[12];
  const float* bw2_b  = (const float*)d_in[13];
  const float* Wd     = (const float*)d_in[14];
  const float* bd     = (const float*)d_in[15];
  float* out = (float*)d_out;

  // pick largest chunk S fitting ws
  auto total_for = [](int S)->size_t{
    size_t fixed = 33554432ull + 67108864ull          // x1t, x2t
                 + 524288ull*2 + 1048576ull           // wipT1f/1b/2f
                 + 524288ull*3                        // wht x3
                 + 12288ull                           // biases
                 + 131072ull + 65536ull               // cstate,hstate (L1)
                 + 65536ull + 32768ull                // cstate2,hstate2
                 + 65536ull + 65536ull;               // h2b + pad slack
    return fixed + 2ull * (size_t)S * 131072ull;      // xwf_c + xwb_c
  };
  int S = 256;
  while (S > 32 && total_for(S) > ws_size) S >>= 1;
  int NC = 1024 / S;

  char* ws = (char*)d_ws;
  size_t o = 0;
  auto alloc = [&](size_t sz){ size_t r = o; o += (sz + 255) & ~(size_t)255; return r; };
  short* x1t    = (short*)(ws + alloc(64ull * 1024 * 256 * 2));   // 32MB
  short* x2t    = (short*)(ws + alloc(64ull * 1024 * 512 * 2));   // 64MB
  short* xwf    = (short*)(ws + alloc((size_t)S * 131072ull));
  short* xwb    = (short*)(ws + alloc((size_t)S * 131072ull));
  short* wipT1f = (short*)(ws + alloc(256ull * 1024 * 2));
  short* wipT1b = (short*)(ws + alloc(256ull * 1024 * 2));
  short* wipT2f = (short*)(ws + alloc(512ull * 1024 * 2));
  short* wht1f  = (short*)(ws + alloc(256ull * 1024 * 2));
  short* wht1b  = (short*)(ws + alloc(256ull * 1024 * 2));
  short* wht2f  = (short*)(ws + alloc(256ull * 1024 * 2));
  float* bp1f   = (float*)(ws + alloc(1024 * 4));
  float* bp1b   = (float*)(ws + alloc(1024 * 4));
  float* bp2f   = (float*)(ws + alloc(1024 * 4));
  float* cst1   = (float*)(ws + alloc(2ull * 64 * 256 * 4));
  short* hst1   = (short*)(ws + alloc(2ull * 64 * 256 * 2));
  float* cst2   = (float*)(ws + alloc(64ull * 256 * 4));
  short* hst2   = (short*)(ws + alloc(64ull * 256 * 2));
  float* h2b    = (float*)(ws + alloc(64ull * 256 * 4));

  const int LDS_RECUR = 151552 + 8192;  // 159744 B
  hipFuncSetAttribute((const void*)&k_recur<1>, hipFuncAttributeMaxDynamicSharedMemorySize, LDS_RECUR);
  hipFuncSetAttribute((const void*)&k_recur<0>, hipFuncAttributeMaxDynamicSharedMemorySize, LDS_RECUR);

  // weight prep
  k_prep_wipT<<<128, 256, 0, stream>>>(fw1_Wi, wipT1f, 256);
  k_prep_wipT<<<128, 256, 0, stream>>>(bw1_Wi, wipT1b, 256);
  k_prep_wipT<<<256, 256, 0, stream>>>(fw2_Wi, wipT2f, 512);
  k_prep_bias<<<4, 256, 0, stream>>>(fw1_b, bp1f);
  k_prep_bias<<<4, 256, 0, stream>>>(bw1_b, bp1b);
  k_prep_bias<<<4, 256, 0, stream>>>(fw2_b, bp2f);
  k_prep_wht<<<128, 256, 0, stream>>>(fw1_Wh, wht1f);
  k_prep_wht<<<128, 256, 0, stream>>>(bw1_Wh, wht1b);
  k_prep_wht<<<128, 256, 0, stream>>>(fw2_Wh, wht2f);

  // embedding gather
  k_gather<<<4096, 256, 0, stream>>>(tokens, embed, x1t);

  dim3 ggrid(S / 2, 8);

  // ---- layer 1, chunked over time ----
  for (int c = 0; c < NC; ++c){
    int t0 = c * S;
    const short* Af = x1t + (size_t)t0 * 64 * 256;                     // fwd rows [t0*64, ...)
    const short* Ab = x1t + (size_t)(1024 - (c + 1) * S) * 64 * 256;   // bwd rows
    k_gemm<256><<<ggrid, 256, 0, stream>>>(Af, wipT1f, bp1f, xwf);
    k_gemm<256><<<ggrid, 256, 0, stream>>>(Ab, wipT1b, bp1b, xwb);
    k_recur<1><<<8, 256, LDS_RECUR, stream>>>(xwf, xwb, wht1f, wht1b,
                                              x2t, cst1, hst1, t0, S, 1, c == 0);
  }

  // ---- layer 2 fwd, chunked ----
  for (int c = 0; c < NC; ++c){
    int t0 = c * S;
    const short* A2 = x2t + (size_t)t0 * 64 * 512;
    k_gemm<512><<<ggrid, 256, 0, stream>>>(A2, wipT2f, bp2f, xwf);
    k_recur<0><<<4, 256, LDS_RECUR, stream>>>(xwf, xwf, wht2f, wht2f,
                                              (short*)nullptr, cst2, hst2, t0, S, 0, c == 0);
  }

  // ---- layer 2 bwd = single step at t=1023 ----
  k_h2b<<<64, 256, 0, stream>>>(x2t, bw2_Wi, bw2_b, h2b);

  // ---- head ----
  k_logits<<<1, 64, 0, stream>>>(hst2, h2b, Wd, bd, out);
}